// Round 1
// baseline (210.179 us; speedup 1.0000x reference)
//
#include <hip/hip_runtime.h>
#include <hip/hip_bf16.h>
#include <stdint.h>

#define N_NODES 100000
#define IN_DIM 256
#define OUT_DIM 128
#define DEG 16

typedef __bf16 bf16x8 __attribute__((ext_vector_type(8)));
typedef __bf16 bf16x4 __attribute__((ext_vector_type(4)));
typedef float f32x4 __attribute__((ext_vector_type(4)));

// ---------------- kernel A: Wt[j][k] = bf16(W[k][j]) ----------------
__global__ void prep_w_kernel(const float* __restrict__ W, __bf16* __restrict__ Wt) {
    const int j = blockIdx.x;   // 0..127 (output col)
    const int k = threadIdx.x;  // 0..255 (input dim)
    Wt[j * IN_DIM + k] = (__bf16)W[k * OUT_DIM + j];
}

// ---------------- kernel B: XP[m][n] = bf16( sum_k X[m][k] * W[k][n] ) ----------------
// block = 256 thr (4 waves). M-tile = 32 rows, N = 128 (wave w -> cols [w*32, w*32+32)).
// X tile staged f32->bf16 into LDS (row pad 256->264 bf16: 528B row stride, 16B-aligned frags).
__global__ __launch_bounds__(256) void gemm_kernel(const float* __restrict__ X,
                                                   const __bf16* __restrict__ Wt,
                                                   __bf16* __restrict__ XP) {
    __shared__ __bf16 Alds[32][264];
    const int m0 = blockIdx.x * 32;
    const int t = threadIdx.x;

    // stage: thread t loads 32 consecutive f32 of one row, converts, writes LDS
    {
        const int row = t >> 3;
        const int seg = (t & 7) * 32;
        const float* src = X + (size_t)(m0 + row) * IN_DIM + seg;
        #pragma unroll
        for (int i = 0; i < 8; ++i) {
            float4 v = *reinterpret_cast<const float4*>(src + i * 4);
            bf16x4 b;
            b[0] = (__bf16)v.x; b[1] = (__bf16)v.y; b[2] = (__bf16)v.z; b[3] = (__bf16)v.w;
            *reinterpret_cast<bf16x4*>(&Alds[row][seg + i * 4]) = b;
        }
    }
    __syncthreads();

    const int lane = t & 63;
    const int wave = t >> 6;
    const int n0 = wave * 32;
    const int lr = lane & 15;   // row (A) / col (B,D) within fragment
    const int lg = lane >> 4;   // k-group / row-group
    f32x4 acc[2][2] = {};

    const __bf16* wbase0 = Wt + (size_t)(n0 + lr) * IN_DIM;
    const __bf16* wbase1 = Wt + (size_t)(n0 + 16 + lr) * IN_DIM;

    #pragma unroll
    for (int kk = 0; kk < IN_DIM; kk += 32) {
        const int ko = kk + lg * 8;
        bf16x8 a0 = *reinterpret_cast<const bf16x8*>(&Alds[lr][ko]);
        bf16x8 a1 = *reinterpret_cast<const bf16x8*>(&Alds[16 + lr][ko]);
        bf16x8 b0 = *reinterpret_cast<const bf16x8*>(wbase0 + ko);
        bf16x8 b1 = *reinterpret_cast<const bf16x8*>(wbase1 + ko);
        acc[0][0] = __builtin_amdgcn_mfma_f32_16x16x32_bf16(a0, b0, acc[0][0], 0, 0, 0);
        acc[0][1] = __builtin_amdgcn_mfma_f32_16x16x32_bf16(a0, b1, acc[0][1], 0, 0, 0);
        acc[1][0] = __builtin_amdgcn_mfma_f32_16x16x32_bf16(a1, b0, acc[1][0], 0, 0, 0);
        acc[1][1] = __builtin_amdgcn_mfma_f32_16x16x32_bf16(a1, b1, acc[1][1], 0, 0, 0);
    }

    // C/D layout (HW-verified): col = lane&15, row = (lane>>4)*4 + r
    #pragma unroll
    for (int mi = 0; mi < 2; ++mi)
        #pragma unroll
        for (int ni = 0; ni < 2; ++ni)
            #pragma unroll
            for (int r = 0; r < 4; ++r) {
                const int row = m0 + mi * 16 + lg * 4 + r;
                const int col = n0 + ni * 16 + lr;
                XP[(size_t)row * OUT_DIM + col] = (__bf16)acc[mi][ni][r];
            }
}

// ---------------- kernel C: fused SDDMM + attention-weighted SpMM ----------------
// one wave per row; lane covers cols {2*lane, 2*lane+1}
__global__ __launch_bounds__(256) void gat_edge_kernel(const __bf16* __restrict__ XP,
                                                       const int* __restrict__ rp,
                                                       const int* __restrict__ ci,
                                                       const float* __restrict__ attw,
                                                       float* __restrict__ out) {
    const int lane = threadIdx.x & 63;
    const int row = blockIdx.x * 4 + (threadIdx.x >> 6);

    float s = 0.f;
    #pragma unroll
    for (int h = 0; h < 8; ++h) s += attw[h];

    const uint32_t xv = *reinterpret_cast<const uint32_t*>(XP + (size_t)row * OUT_DIM + lane * 2);
    const float x0 = __uint_as_float(xv << 16);
    const float x1 = __uint_as_float(xv & 0xffff0000u);

    float acc0 = 0.f, acc1 = 0.f;
    const int e0 = rp[row], e1 = rp[row + 1];
    for (int e = e0; e < e1; ++e) {
        const int c = ci[e];
        const uint32_t dv = *reinterpret_cast<const uint32_t*>(XP + (size_t)c * OUT_DIM + lane * 2);
        const float d0 = __uint_as_float(dv << 16);
        const float d1 = __uint_as_float(dv & 0xffff0000u);
        float p = x0 * d0 + x1 * d1;
        #pragma unroll
        for (int off = 32; off >= 1; off >>= 1) p += __shfl_xor(p, off);
        const float att = p * s;
        acc0 += att * d0;
        acc1 += att * d1;
    }
    float2 o; o.x = acc0; o.y = acc1;
    *reinterpret_cast<float2*>(out + (size_t)row * OUT_DIM + lane * 2) = o;
}

// ---------------- launch ----------------
extern "C" void kernel_launch(void* const* d_in, const int* in_sizes, int n_in,
                              void* d_out, int out_size, void* d_ws, size_t ws_size,
                              hipStream_t stream) {
    const float* X    = (const float*)d_in[0];
    const float* W    = (const float*)d_in[1];
    const float* attw = (const float*)d_in[2];
    const int*   rp   = (const int*)d_in[3];
    const int*   ci   = (const int*)d_in[4];
    float* out = (float*)d_out;

    // workspace: XP bf16 [100000][128] then Wt bf16 [128][256]
    __bf16* XP = (__bf16*)d_ws;
    __bf16* Wt = (__bf16*)((char*)d_ws + (size_t)N_NODES * OUT_DIM * 2);

    prep_w_kernel<<<OUT_DIM, IN_DIM, 0, stream>>>(W, Wt);
    gemm_kernel<<<N_NODES / 32, 256, 0, stream>>>(X, Wt, XP);
    gat_edge_kernel<<<N_NODES / 4, 256, 0, stream>>>(XP, rp, ci, attw, out);
}

// Round 2
// 108.373 us; speedup vs baseline: 1.9394x; 1.9394x over previous
//
#include <hip/hip_runtime.h>
#include <hip/hip_bf16.h>
#include <stdint.h>

#define N_NODES 100000
#define IN_DIM 256
#define OUT_DIM 128
#define DEG 16

typedef __bf16 bf16x8 __attribute__((ext_vector_type(8)));
typedef __bf16 bf16x4 __attribute__((ext_vector_type(4)));
typedef float f32x4 __attribute__((ext_vector_type(4)));

// ---------------- kernel A: Wt[j][k] = bf16(W[k][j]) ----------------
__global__ void prep_w_kernel(const float* __restrict__ W, __bf16* __restrict__ Wt) {
    const int j = blockIdx.x;   // 0..127 (output col)
    const int k = threadIdx.x;  // 0..255 (input dim)
    Wt[j * IN_DIM + k] = (__bf16)W[k * OUT_DIM + j];
}

// ---------------- kernel B: XP[m][n] = bf16( sum_k X[m][k] * W[k][n] ) ----------------
__global__ __launch_bounds__(256) void gemm_kernel(const float* __restrict__ X,
                                                   const __bf16* __restrict__ Wt,
                                                   __bf16* __restrict__ XP) {
    __shared__ __bf16 Alds[32][264];
    const int m0 = blockIdx.x * 32;
    const int t = threadIdx.x;

    {
        const int row = t >> 3;
        const int seg = (t & 7) * 32;
        const float* src = X + (size_t)(m0 + row) * IN_DIM + seg;
        #pragma unroll
        for (int i = 0; i < 8; ++i) {
            float4 v = *reinterpret_cast<const float4*>(src + i * 4);
            bf16x4 b;
            b[0] = (__bf16)v.x; b[1] = (__bf16)v.y; b[2] = (__bf16)v.z; b[3] = (__bf16)v.w;
            *reinterpret_cast<bf16x4*>(&Alds[row][seg + i * 4]) = b;
        }
    }
    __syncthreads();

    const int lane = t & 63;
    const int wave = t >> 6;
    const int n0 = wave * 32;
    const int lr = lane & 15;
    const int lg = lane >> 4;
    f32x4 acc[2][2] = {};

    const __bf16* wbase0 = Wt + (size_t)(n0 + lr) * IN_DIM;
    const __bf16* wbase1 = Wt + (size_t)(n0 + 16 + lr) * IN_DIM;

    #pragma unroll
    for (int kk = 0; kk < IN_DIM; kk += 32) {
        const int ko = kk + lg * 8;
        bf16x8 a0 = *reinterpret_cast<const bf16x8*>(&Alds[lr][ko]);
        bf16x8 a1 = *reinterpret_cast<const bf16x8*>(&Alds[16 + lr][ko]);
        bf16x8 b0 = *reinterpret_cast<const bf16x8*>(wbase0 + ko);
        bf16x8 b1 = *reinterpret_cast<const bf16x8*>(wbase1 + ko);
        acc[0][0] = __builtin_amdgcn_mfma_f32_16x16x32_bf16(a0, b0, acc[0][0], 0, 0, 0);
        acc[0][1] = __builtin_amdgcn_mfma_f32_16x16x32_bf16(a0, b1, acc[0][1], 0, 0, 0);
        acc[1][0] = __builtin_amdgcn_mfma_f32_16x16x32_bf16(a1, b0, acc[1][0], 0, 0, 0);
        acc[1][1] = __builtin_amdgcn_mfma_f32_16x16x32_bf16(a1, b1, acc[1][1], 0, 0, 0);
    }

    #pragma unroll
    for (int mi = 0; mi < 2; ++mi)
        #pragma unroll
        for (int ni = 0; ni < 2; ++ni)
            #pragma unroll
            for (int r = 0; r < 4; ++r) {
                const int row = m0 + mi * 16 + lg * 4 + r;
                const int col = n0 + ni * 16 + lr;
                XP[(size_t)row * OUT_DIM + col] = (__bf16)acc[mi][ni][r];
            }
}

// ---------------- kernel C: fused SDDMM + attention-weighted SpMM ----------------
// One wave per row. 4 groups of 16 lanes; group g owns edges [g*4, g*4+4);
// lane sl=lane&15 covers cols [sl*8, sl*8+8). All 4 gathers per group issue
// back-to-back (16 loads in flight per wave); dot-reduce is 4-deep xor-shfl
// with 4 independent chains; final 2-step cross-group reduce.
__global__ __launch_bounds__(256) void gat_edge_kernel(const __bf16* __restrict__ XP,
                                                       const int* __restrict__ rp,
                                                       const int* __restrict__ ci,
                                                       const float* __restrict__ attw,
                                                       float* __restrict__ out) {
    const int lane = threadIdx.x & 63;
    const int row = blockIdx.x * 4 + (threadIdx.x >> 6);
    const int g = lane >> 4;    // group 0..3
    const int sl = lane & 15;   // sub-lane: cols sl*8..sl*8+8

    float s = 0.f;
    #pragma unroll
    for (int h = 0; h < 8; ++h) s += attw[h];

    // own row slice: 8 bf16 -> 8 f32
    float x[8];
    {
        uint4 xv = *reinterpret_cast<const uint4*>(XP + (size_t)row * OUT_DIM + sl * 8);
        const uint32_t* xw = reinterpret_cast<const uint32_t*>(&xv);
        #pragma unroll
        for (int i = 0; i < 4; ++i) {
            x[2 * i]     = __uint_as_float(xw[i] << 16);
            x[2 * i + 1] = __uint_as_float(xw[i] & 0xffff0000u);
        }
    }

    // 4 edge indices for this group (one 16B broadcast load)
    const int4 cv = reinterpret_cast<const int4*>(ci + (size_t)row * DEG)[g];
    const int c[4] = {cv.x, cv.y, cv.z, cv.w};

    // gather 4 dst slices (issue all loads before converting)
    uint4 dvu[4];
    #pragma unroll
    for (int j = 0; j < 4; ++j)
        dvu[j] = *reinterpret_cast<const uint4*>(XP + (size_t)c[j] * OUT_DIM + sl * 8);

    float d[4][8];
    #pragma unroll
    for (int j = 0; j < 4; ++j) {
        const uint32_t* dw = reinterpret_cast<const uint32_t*>(&dvu[j]);
        #pragma unroll
        for (int i = 0; i < 4; ++i) {
            d[j][2 * i]     = __uint_as_float(dw[i] << 16);
            d[j][2 * i + 1] = __uint_as_float(dw[i] & 0xffff0000u);
        }
    }

    // per-edge partial dots
    float p[4];
    #pragma unroll
    for (int j = 0; j < 4; ++j) {
        float t0 = 0.f;
        #pragma unroll
        for (int i = 0; i < 8; ++i) t0 += x[i] * d[j][i];
        p[j] = t0;
    }
    // 4-deep reduce across the 16-lane group, 4 independent chains
    #pragma unroll
    for (int off = 1; off <= 8; off <<= 1) {
        #pragma unroll
        for (int j = 0; j < 4; ++j) p[j] += __shfl_xor(p[j], off);
    }

    // accumulate att-weighted dst
    float acc[8] = {};
    #pragma unroll
    for (int j = 0; j < 4; ++j) {
        const float att = p[j] * s;
        #pragma unroll
        for (int i = 0; i < 8; ++i) acc[i] += att * d[j][i];
    }

    // cross-group reduce (xor 16, 32)
    #pragma unroll
    for (int off = 16; off <= 32; off <<= 1) {
        #pragma unroll
        for (int i = 0; i < 8; ++i) acc[i] += __shfl_xor(acc[i], off);
    }

    if (g == 0) {
        float4 o0, o1;
        o0.x = acc[0]; o0.y = acc[1]; o0.z = acc[2]; o0.w = acc[3];
        o1.x = acc[4]; o1.y = acc[5]; o1.z = acc[6]; o1.w = acc[7];
        float* dst = out + (size_t)row * OUT_DIM + sl * 8;
        *reinterpret_cast<float4*>(dst) = o0;
        *reinterpret_cast<float4*>(dst + 4) = o1;
    }
}

// ---------------- launch ----------------
extern "C" void kernel_launch(void* const* d_in, const int* in_sizes, int n_in,
                              void* d_out, int out_size, void* d_ws, size_t ws_size,
                              hipStream_t stream) {
    const float* X    = (const float*)d_in[0];
    const float* W    = (const float*)d_in[1];
    const float* attw = (const float*)d_in[2];
    const int*   rp   = (const int*)d_in[3];
    const int*   ci   = (const int*)d_in[4];
    float* out = (float*)d_out;

    __bf16* XP = (__bf16*)d_ws;
    __bf16* Wt = (__bf16*)((char*)d_ws + (size_t)N_NODES * OUT_DIM * 2);

    prep_w_kernel<<<OUT_DIM, IN_DIM, 0, stream>>>(W, Wt);
    gemm_kernel<<<N_NODES / 32, 256, 0, stream>>>(X, Wt, XP);
    gat_edge_kernel<<<N_NODES / 4, 256, 0, stream>>>(XP, rp, ci, attw, out);
}